// Round 1
// baseline (275.424 us; speedup 1.0000x reference)
//
#include <hip/hip_runtime.h>
#include <math.h>

// HoltWintersDecomposition: x (8192, 2048, 1) f32; scalars logit_alpha, logit_gamma.
// Sequential recurrence over t per row; rows independent.
// One thread per row, 64 rows per block (1 wave), LDS-staged tiles of 64 time steps
// for coalesced global I/O. y overwrites the x tile in place.

constexpr int T    = 2048;
constexpr int B    = 8192;
constexpr int RPB  = 64;       // rows per block (= block size, one wave)
constexpr int TT   = 64;       // time-tile width
constexpr int LS   = TT + 1;   // LDS stride: +1 pad -> bank = (row + t) % 32, 2-way (free)
constexpr float EPS = 1e-8f;

__global__ __launch_bounds__(64, 1)
void hw_scan_kernel(const float* __restrict__ x,
                    const float* __restrict__ pla,
                    const float* __restrict__ plg,
                    float* __restrict__ out)
{
    __shared__ float xs [RPB][LS];   // x tile, overwritten with y during compute
    __shared__ float lls[RPB][LS];   // level tile
    __shared__ float sss[RPB][LS];   // season tile

    const int tid  = threadIdx.x;        // 0..63
    const int row0 = blockIdx.x * RPB;

    const float alpha   = 1.0f / (1.0f + expf(-pla[0]));
    const float gamma   = 1.0f / (1.0f + expf(-plg[0]));
    const float one_m_a = 1.0f - alpha;
    const float one_m_g = 1.0f - gamma;

    float* __restrict__ level  = out;
    float* __restrict__ season = out + (size_t)B * T;
    float* __restrict__ yout   = out + (size_t)2 * B * T;

    // staging decomposition: lane -> (row-within-4, float4-slot)
    const int rl = tid >> 4;            // 0..3
    const int t4 = (tid & 15) << 2;     // 0,4,...,60 (float index; 16B aligned)

    float4 pre[16];
    // prologue: prefetch tile 0 (coalesced: 16 consecutive float4 per 16-lane group)
    #pragma unroll
    for (int c = 0; c < 16; ++c) {
        const int r = rl + (c << 2);
        pre[c] = *reinterpret_cast<const float4*>(&x[(size_t)(row0 + r) * T + t4]);
    }

    float lp = 0.0f, sp = 1.0f;   // carried state (set properly at t==0)

    for (int t0 = 0; t0 < T; t0 += TT) {
        // ---- write prefetched tile into LDS (scalar writes keep banks clean with +1 pad)
        #pragma unroll
        for (int c = 0; c < 16; ++c) {
            const int r = rl + (c << 2);
            xs[r][t4 + 0] = pre[c].x;
            xs[r][t4 + 1] = pre[c].y;
            xs[r][t4 + 2] = pre[c].z;
            xs[r][t4 + 3] = pre[c].w;
        }
        __syncthreads();

        // ---- prefetch next tile (hides HBM latency under the compute phase)
        if (t0 + TT < T) {
            #pragma unroll
            for (int c = 0; c < 16; ++c) {
                const int r = rl + (c << 2);
                pre[c] = *reinterpret_cast<const float4*>(
                    &x[(size_t)(row0 + r) * T + (t0 + TT) + t4]);
            }
        }

        // ---- compute: thread `tid` owns row (row0 + tid); sequential over tile
        #define HW_STEP(tt_)                                                   \
            {                                                                  \
                const float xt = xs[tid][tt_];                                 \
                const float lt = alpha * (xt / (sp + EPS)) + one_m_a * lp;     \
                const float st = gamma * (xt / (lt + EPS)) + one_m_g * sp;     \
                const float yt = xt / (lt * st + EPS);                         \
                lls[tid][tt_] = lt;                                            \
                sss[tid][tt_] = st;                                            \
                xs [tid][tt_] = yt;                                            \
                lp = lt; sp = st;                                              \
            }

        if (t0 == 0) {
            // t == 0 special case: l0 = x0, s0 = 1
            {
                const float xt = xs[tid][0];
                const float lt = xt;
                const float st = 1.0f;
                const float yt = xt / (lt * st + EPS);
                lls[tid][0] = lt;
                sss[tid][0] = st;
                xs [tid][0] = yt;
                lp = lt; sp = st;
            }
            for (int tt = 1; tt < TT; ++tt) HW_STEP(tt)
        } else {
            for (int tt = 0; tt < TT; ++tt) HW_STEP(tt)
        }
        #undef HW_STEP
        __syncthreads();

        // ---- store tile: coalesced float4 stores for level/season/y
        #pragma unroll
        for (int c = 0; c < 16; ++c) {
            const int r = rl + (c << 2);
            const size_t g = (size_t)(row0 + r) * T + t0 + t4;
            float4 vl, vs, vy;
            vl.x = lls[r][t4 + 0]; vl.y = lls[r][t4 + 1];
            vl.z = lls[r][t4 + 2]; vl.w = lls[r][t4 + 3];
            vs.x = sss[r][t4 + 0]; vs.y = sss[r][t4 + 1];
            vs.z = sss[r][t4 + 2]; vs.w = sss[r][t4 + 3];
            vy.x = xs [r][t4 + 0]; vy.y = xs [r][t4 + 1];
            vy.z = xs [r][t4 + 2]; vy.w = xs [r][t4 + 3];
            *reinterpret_cast<float4*>(&level [g]) = vl;
            *reinterpret_cast<float4*>(&season[g]) = vs;
            *reinterpret_cast<float4*>(&yout  [g]) = vy;
        }
        __syncthreads();
    }
}

extern "C" void kernel_launch(void* const* d_in, const int* in_sizes, int n_in,
                              void* d_out, int out_size, void* d_ws, size_t ws_size,
                              hipStream_t stream) {
    const float* x   = (const float*)d_in[0];
    const float* pla = (const float*)d_in[1];
    const float* plg = (const float*)d_in[2];
    float* out = (float*)d_out;

    dim3 grid(B / RPB);   // 128 blocks
    dim3 block(RPB);      // 64 threads = 1 wave
    hw_scan_kernel<<<grid, block, 0, stream>>>(x, pla, plg, out);
}

// Round 2
// 128.032 us; speedup vs baseline: 2.1512x; 2.1512x over previous
//
#include <hip/hip_runtime.h>
#include <math.h>

// HoltWintersDecomposition: x (8192, 2048) f32, sequential recurrence per row.
// One thread per row, 256 blocks x 32 threads (half-masked waves) so all 256 CUs
// carry HBM traffic. No LDS: per-lane float4 loads/stores on the lane's own row
// (4 consecutive float4 = one 64B line; L1 merges loads, L2 write-combines stores).
// Chain shortened via v_rcp_f32 + 1 Newton (states) and raw rcp (y output).

constexpr int   T    = 2048;
constexpr int   B    = 8192;
constexpr int   CH   = 16;        // steps per chunk (= one 64B line of x)
constexpr int   NCH  = T / CH;    // 128 chunks
constexpr float EPS  = 1e-8f;

__device__ __forceinline__ float rcp_nr(float d) {
    float r = __builtin_amdgcn_rcpf(d);
    float e = __builtin_fmaf(-d, r, 1.0f);   // e = 1 - d*r
    return __builtin_fmaf(r, e, r);          // r' = r + r*e  (~1 ulp)
}
__device__ __forceinline__ float rcp_raw(float d) {
    return __builtin_amdgcn_rcpf(d);         // ~2.5e-7 rel, y-output only
}

__device__ __forceinline__ void hw_step(float xt, float& lp, float& sp,
                                        float alpha, float gamma,
                                        float oma, float omg,
                                        float& lo, float& so, float& yo) {
    const float rs = rcp_nr(sp + EPS);
    const float lt = __builtin_fmaf(alpha * xt, rs, oma * lp);
    const float rl = rcp_nr(lt + EPS);
    const float st = __builtin_fmaf(gamma * xt, rl, omg * sp);
    const float yt = xt * rcp_raw(__builtin_fmaf(lt, st, EPS));
    lo = lt; so = st; yo = yt;
    lp = lt; sp = st;
}

template <bool FIRST>
__device__ __forceinline__ void chunk16(const float4* xb,
                                        float& lp, float& sp,
                                        float alpha, float gamma,
                                        float oma, float omg,
                                        float* __restrict__ lrow,
                                        float* __restrict__ srow,
                                        float* __restrict__ yrow,
                                        int t0) {
    #pragma unroll
    for (int q = 0; q < 4; ++q) {
        const float4 xv = xb[q];
        float4 lv, sv, yv;
        if (FIRST && q == 0) {
            // t == 0: l0 = x0, s0 = 1, y0 = x0 / (x0 + eps)
            const float xt = xv.x;
            lp = xt; sp = 1.0f;
            lv.x = xt; sv.x = 1.0f;
            yv.x = xt * rcp_raw(xt + EPS);
            hw_step(xv.y, lp, sp, alpha, gamma, oma, omg, lv.y, sv.y, yv.y);
            hw_step(xv.z, lp, sp, alpha, gamma, oma, omg, lv.z, sv.z, yv.z);
            hw_step(xv.w, lp, sp, alpha, gamma, oma, omg, lv.w, sv.w, yv.w);
        } else {
            hw_step(xv.x, lp, sp, alpha, gamma, oma, omg, lv.x, sv.x, yv.x);
            hw_step(xv.y, lp, sp, alpha, gamma, oma, omg, lv.y, sv.y, yv.y);
            hw_step(xv.z, lp, sp, alpha, gamma, oma, omg, lv.z, sv.z, yv.z);
            hw_step(xv.w, lp, sp, alpha, gamma, oma, omg, lv.w, sv.w, yv.w);
        }
        const int t = t0 + q * 4;
        *reinterpret_cast<float4*>(lrow + t) = lv;
        *reinterpret_cast<float4*>(srow + t) = sv;
        *reinterpret_cast<float4*>(yrow + t) = yv;
    }
}

__global__ __launch_bounds__(32, 1)
void hw_kernel(const float* __restrict__ x,
               const float* __restrict__ pla,
               const float* __restrict__ plg,
               float* __restrict__ out)
{
    const int row = blockIdx.x * 32 + threadIdx.x;

    const float alpha = 1.0f / (1.0f + expf(-pla[0]));
    const float gamma = 1.0f / (1.0f + expf(-plg[0]));
    const float oma = 1.0f - alpha;
    const float omg = 1.0f - gamma;

    const float* __restrict__ xrow = x   + (size_t)row * T;
    float* __restrict__ lrow = out + (size_t)row * T;
    float* __restrict__ srow = out + (size_t)(B + row) * T;
    float* __restrict__ yrow = out + (size_t)(2 * B + row) * T;

    float4 bufA[4], bufB[4];
    #pragma unroll
    for (int k = 0; k < 4; ++k)
        bufA[k] = *reinterpret_cast<const float4*>(xrow + k * 4);
    #pragma unroll
    for (int k = 0; k < 4; ++k)
        bufB[k] = *reinterpret_cast<const float4*>(xrow + CH + k * 4);

    float lp = 0.0f, sp = 1.0f;

    // chunk 0 (t==0 special), then refill A with chunk 2
    chunk16<true>(bufA, lp, sp, alpha, gamma, oma, omg, lrow, srow, yrow, 0);
    #pragma unroll
    for (int k = 0; k < 4; ++k)
        bufA[k] = *reinterpret_cast<const float4*>(xrow + 2 * CH + k * 4);

    // main loop: chunks 1..126 in pairs; buffers stay statically indexed
    for (int c = 1; c < NCH - 1; c += 2) {
        chunk16<false>(bufB, lp, sp, alpha, gamma, oma, omg, lrow, srow, yrow, c * CH);
        {
            const int cn = (c + 2 < NCH) ? c + 2 : NCH - 1;
            const float* p = xrow + cn * CH;
            #pragma unroll
            for (int k = 0; k < 4; ++k)
                bufB[k] = *reinterpret_cast<const float4*>(p + k * 4);
        }
        chunk16<false>(bufA, lp, sp, alpha, gamma, oma, omg, lrow, srow, yrow, (c + 1) * CH);
        {
            const int cn = (c + 3 < NCH) ? c + 3 : NCH - 1;
            const float* p = xrow + cn * CH;
            #pragma unroll
            for (int k = 0; k < 4; ++k)
                bufA[k] = *reinterpret_cast<const float4*>(p + k * 4);
        }
    }

    // tail: chunk 127 (sits in bufB after the loop)
    chunk16<false>(bufB, lp, sp, alpha, gamma, oma, omg, lrow, srow, yrow, (NCH - 1) * CH);
}

extern "C" void kernel_launch(void* const* d_in, const int* in_sizes, int n_in,
                              void* d_out, int out_size, void* d_ws, size_t ws_size,
                              hipStream_t stream) {
    const float* x   = (const float*)d_in[0];
    const float* pla = (const float*)d_in[1];
    const float* plg = (const float*)d_in[2];
    float* out = (float*)d_out;

    dim3 grid(B / 32);   // 256 blocks -> one per CU
    dim3 block(32);      // half-masked wave; all 8192 rows covered exactly
    hw_kernel<<<grid, block, 0, stream>>>(x, pla, plg, out);
}